// Round 7
// baseline (197.158 us; speedup 1.0000x reference)
//
#include <hip/hip_runtime.h>

#define D 64
#define K 1024
#define NPTS 65536
#define OUT_ELEMS (NPTS * D)
#define PAD4 17  // LDS out-slab row stride in float4 units

// ---------------------------------------------------------------------------
// Prep: LDS-tiled transpose emb[D][K] -> eT[K][D] (coalesced both sides);
// enorm[k] = ||e_k||^2 in numpy axis-0 (sequential d) order; zero loss slot.
// 16 blocks x 256 threads; block handles 64 consecutive k.
// ---------------------------------------------------------------------------
__global__ __launch_bounds__(256) void vq_prep(const float* __restrict__ emb,
                                               float* __restrict__ eT,
                                               float* __restrict__ enorm,
                                               float* __restrict__ loss_out) {
    __shared__ float tile[64][65];
    const int t    = threadIdx.x;
    const int lane = t & 63;
    const int quad = t >> 6;
    const int k0   = blockIdx.x * 64;

#pragma unroll
    for (int i = 0; i < 16; ++i) {
        const int d = i * 4 + quad;
        tile[d][lane] = emb[d * K + k0 + lane];   // 256B contiguous per wave
    }
    __syncthreads();

    // Store: t -> (kk = t>>2, c = t&3); each thread writes 16 consecutive
    // floats of row k0+kk; ascending t = ascending addresses (coalesced).
    const int kk = t >> 2, c = t & 3;
    float4* dst = (float4*)(eT + (size_t)(k0 + kk) * D + c * 16);
#pragma unroll
    for (int j = 0; j < 4; ++j) {
        dst[j] = make_float4(tile[c * 16 + 4 * j + 0][kk],
                             tile[c * 16 + 4 * j + 1][kk],
                             tile[c * 16 + 4 * j + 2][kk],
                             tile[c * 16 + 4 * j + 3][kk]);
    }

    if (t < 64) {   // np add.reduce axis 0: sequential over d
        float s = __fmul_rn(tile[0][t], tile[0][t]);
        for (int dd = 1; dd < D; ++dd)
            s = __fadd_rn(s, __fmul_rn(tile[dd][t], tile[dd][t]));
        enorm[k0 + t] = s;
    }
    if (blockIdx.x == 0 && t == 0) *loss_out = 0.0f;
}

// numpy pairwise_sum partial: sequential adds of 8 squared terms
__device__ __forceinline__ float sq8(float a, float b, float c, float d,
                                     float e, float f, float g, float h) {
    float r = __fmul_rn(a, a);
    r = __fadd_rn(r, __fmul_rn(b, b));
    r = __fadd_rn(r, __fmul_rn(c, c));
    r = __fadd_rn(r, __fmul_rn(d, d));
    r = __fadd_rn(r, __fmul_rn(e, e));
    r = __fadd_rn(r, __fmul_rn(f, f));
    r = __fadd_rn(r, __fmul_rn(g, g));
    r = __fadd_rn(r, __fmul_rn(h, h));
    return r;
}

// Opaque register pin: asm def cannot be rematerialized.
#define PIN4(v) asm volatile("" : "+v"(v.x), "+v"(v.y), "+v"(v.z), "+v"(v.w))

// ---------------------------------------------------------------------------
// Main: block = 256 thr = 4 waves, owns 128 points — TWO per lane
// (p0 = blk*128+lane, p1 = p0+64). Each e-row fetch (scalarized to
// s_load_dwordx16, SGPR-resident via the uniform-w readfirstlane trick)
// now feeds 128 MACs instead of 64: SMEM instrs/MAC and per-code epilogue
// overhead halve vs R5. Plain fmaf (v_fmac_f32 saturates the fp32 rate on
// CDNA4 SIMD-32; packing is rate-neutral and cost movs in R5). 8 independent
// acc chains give ILP >> 4-cyc dep latency. Split-K 4x256; LDS combine;
// coalesced slab write; wave 0 computes the loss for both halves.
// ---------------------------------------------------------------------------
__global__ __launch_bounds__(256, 2) void vq_main(const float* __restrict__ x,
                                                  const float* __restrict__ eT,
                                                  const float* __restrict__ enorm,
                                                  float* __restrict__ out,
                                                  float* __restrict__ loss_out) {
    __shared__ float4 slab[128 * PAD4];   // output staging (34.8 KiB)
    __shared__ float  sdist[4][128];
    __shared__ int    sidx[4][128];

    const int t    = threadIdx.x;
    const int lane = t & 63;
    const int w    = __builtin_amdgcn_readfirstlane(t >> 6);  // 0..3, uniform

    // Two x rows -> 32 named float4 registers, pinned.
    const float4* xr0 = (const float4*)(x + ((size_t)blockIdx.x * 128 + lane) * D);
    const float4* xr1 = xr0 + 64 * (D / 4);   // point p0 + 64
    float4 a0 = xr0[0],  a1 = xr0[1],  a2 = xr0[2],  a3 = xr0[3];
    float4 a4 = xr0[4],  a5 = xr0[5],  a6 = xr0[6],  a7 = xr0[7];
    float4 a8 = xr0[8],  a9 = xr0[9],  a10 = xr0[10], a11 = xr0[11];
    float4 a12 = xr0[12], a13 = xr0[13], a14 = xr0[14], a15 = xr0[15];
    float4 b0 = xr1[0],  b1 = xr1[1],  b2 = xr1[2],  b3 = xr1[3];
    float4 b4 = xr1[4],  b5 = xr1[5],  b6 = xr1[6],  b7 = xr1[7];
    float4 b8 = xr1[8],  b9 = xr1[9],  b10 = xr1[10], b11 = xr1[11];
    float4 b12 = xr1[12], b13 = xr1[13], b14 = xr1[14], b15 = xr1[15];
    PIN4(a0);  PIN4(a1);  PIN4(a2);  PIN4(a3);
    PIN4(a4);  PIN4(a5);  PIN4(a6);  PIN4(a7);
    PIN4(a8);  PIN4(a9);  PIN4(a10); PIN4(a11);
    PIN4(a12); PIN4(a13); PIN4(a14); PIN4(a15);
    PIN4(b0);  PIN4(b1);  PIN4(b2);  PIN4(b3);
    PIN4(b4);  PIN4(b5);  PIN4(b6);  PIN4(b7);
    PIN4(b8);  PIN4(b9);  PIN4(b10); PIN4(b11);
    PIN4(b12); PIN4(b13); PIN4(b14); PIN4(b15);

    // ||x||^2 per point, numpy pairwise order (same as R2-R5, proven).
    const float p0r0 = sq8(a0.x, a2.x, a4.x, a6.x, a8.x, a10.x, a12.x, a14.x);
    const float p0r1 = sq8(a0.y, a2.y, a4.y, a6.y, a8.y, a10.y, a12.y, a14.y);
    const float p0r2 = sq8(a0.z, a2.z, a4.z, a6.z, a8.z, a10.z, a12.z, a14.z);
    const float p0r3 = sq8(a0.w, a2.w, a4.w, a6.w, a8.w, a10.w, a12.w, a14.w);
    const float p0r4 = sq8(a1.x, a3.x, a5.x, a7.x, a9.x, a11.x, a13.x, a15.x);
    const float p0r5 = sq8(a1.y, a3.y, a5.y, a7.y, a9.y, a11.y, a13.y, a15.y);
    const float p0r6 = sq8(a1.z, a3.z, a5.z, a7.z, a9.z, a11.z, a13.z, a15.z);
    const float p0r7 = sq8(a1.w, a3.w, a5.w, a7.w, a9.w, a11.w, a13.w, a15.w);
    const float A0n = __fadd_rn(
        __fadd_rn(__fadd_rn(p0r0, p0r1), __fadd_rn(p0r2, p0r3)),
        __fadd_rn(__fadd_rn(p0r4, p0r5), __fadd_rn(p0r6, p0r7)));
    const float p1r0 = sq8(b0.x, b2.x, b4.x, b6.x, b8.x, b10.x, b12.x, b14.x);
    const float p1r1 = sq8(b0.y, b2.y, b4.y, b6.y, b8.y, b10.y, b12.y, b14.y);
    const float p1r2 = sq8(b0.z, b2.z, b4.z, b6.z, b8.z, b10.z, b12.z, b14.z);
    const float p1r3 = sq8(b0.w, b2.w, b4.w, b6.w, b8.w, b10.w, b12.w, b14.w);
    const float p1r4 = sq8(b1.x, b3.x, b5.x, b7.x, b9.x, b11.x, b13.x, b15.x);
    const float p1r5 = sq8(b1.y, b3.y, b5.y, b7.y, b9.y, b11.y, b13.y, b15.y);
    const float p1r6 = sq8(b1.z, b3.z, b5.z, b7.z, b9.z, b11.z, b13.z, b15.z);
    const float p1r7 = sq8(b1.w, b3.w, b5.w, b7.w, b9.w, b11.w, b13.w, b15.w);
    const float A1n = __fadd_rn(
        __fadd_rn(__fadd_rn(p1r0, p1r1), __fadd_rn(p1r2, p1r3)),
        __fadd_rn(__fadd_rn(p1r4, p1r5), __fadd_rn(p1r6, p1r7)));

    // Scan this wave's 256-code chunk.
    float best0 = 3.402823466e38f, best1 = 3.402823466e38f;
    int   bi0 = 0, bi1 = 0;
    const int k0 = w * 256;
    for (int kk = 0; kk < 256; ++kk) {
        const int k = k0 + kk;
        const float4* er = (const float4*)(eT + (size_t)k * D);  // uniform
        const float4 E0 = er[0],  E1 = er[1],  E2 = er[2],  E3 = er[3];
        const float4 E4 = er[4],  E5 = er[5],  E6 = er[6],  E7 = er[7];
        const float4 E8 = er[8],  E9 = er[9],  E10 = er[10], E11 = er[11];
        const float4 E12 = er[12], E13 = er[13], E14 = er[14], E15 = er[15];
        const float enk = enorm[k];
        float ax = 0.f, ay = 0.f, az = 0.f, aw = 0.f;   // point 0 chains
        float bx = 0.f, by = 0.f, bz = 0.f, bw = 0.f;   // point 1 chains
#define FSTEP(J) {                                        \
        ax = fmaf(a##J.x, E##J.x, ax);                    \
        ay = fmaf(a##J.y, E##J.y, ay);                    \
        az = fmaf(a##J.z, E##J.z, az);                    \
        aw = fmaf(a##J.w, E##J.w, aw);                    \
        bx = fmaf(b##J.x, E##J.x, bx);                    \
        by = fmaf(b##J.y, E##J.y, by);                    \
        bz = fmaf(b##J.z, E##J.z, bz);                    \
        bw = fmaf(b##J.w, E##J.w, bw); }
        FSTEP(0) FSTEP(1) FSTEP(2) FSTEP(3)
        FSTEP(4) FSTEP(5) FSTEP(6) FSTEP(7)
        FSTEP(8) FSTEP(9) FSTEP(10) FSTEP(11)
        FSTEP(12) FSTEP(13) FSTEP(14) FSTEP(15)
#undef FSTEP
        const float dot0  = __fadd_rn(__fadd_rn(ax, ay), __fadd_rn(az, aw));
        const float dot1  = __fadd_rn(__fadd_rn(bx, by), __fadd_rn(bz, bw));
        const float dist0 = __fsub_rn(__fadd_rn(A0n, enk), __fmul_rn(2.0f, dot0));
        const float dist1 = __fsub_rn(__fadd_rn(A1n, enk), __fmul_rn(2.0f, dot1));
        if (dist0 < best0) { best0 = dist0; bi0 = k; }   // strict <: first-index
        if (dist1 < best1) { best1 = dist1; bi1 = k; }
    }

    sdist[w][lane]      = best0;
    sidx[w][lane]       = bi0;
    sdist[w][64 + lane] = best1;
    sidx[w][64 + lane]  = bi1;
    __syncthreads();

    // 2 threads per point: combine the 4 wave candidates (ascending w =
    // ascending k keeps first-index ties), gather winner half-row into slab.
    {
        const int p = t >> 1;
        const int c = t & 1;
        float fb = sdist[0][p];
        int   fi = sidx[0][p];
#pragma unroll
        for (int ww = 1; ww < 4; ++ww) {
            const float dv = sdist[ww][p];
            const int   iv = sidx[ww][p];
            if (dv < fb) { fb = dv; fi = iv; }
        }
        const float4* qr = (const float4*)(eT + (size_t)fi * D) + c * 8;
        float4* dst = &slab[p * PAD4 + c * 8];
#pragma unroll
        for (int jj = 0; jj < 8; ++jj) dst[jj] = qr[jj];
    }
    __syncthreads();

    // Coalesced write of the block's output slab (32 KiB = 2048 float4).
    float4* og = (float4*)out + (size_t)blockIdx.x * 2048;
#pragma unroll
    for (int s = 0; s < 8; ++s) {
        const int f = s * 256 + t;
        og[f] = slab[(f >> 4) * PAD4 + (f & 15)];
    }

    // Loss: wave 0 covers both of its lane's points (compile-time x indices).
    if (w == 0) {
        const float4* q0 = &slab[lane * PAD4];
        const float4* q1 = &slab[(64 + lane) * PAD4];
        float ls = 0.f;
#define LSTEP(QP, XJ) { const float4 q = (QP); const float4 xv = (XJ); \
        const float dx = q.x - xv.x;                      \
        const float dy = q.y - xv.y;                      \
        const float dz = q.z - xv.z;                      \
        const float dw = q.w - xv.w;                      \
        ls = fmaf(dx, dx, ls); ls = fmaf(dy, dy, ls);     \
        ls = fmaf(dz, dz, ls); ls = fmaf(dw, dw, ls); }
        LSTEP(q0[0],  a0)  LSTEP(q0[1],  a1)  LSTEP(q0[2],  a2)  LSTEP(q0[3],  a3)
        LSTEP(q0[4],  a4)  LSTEP(q0[5],  a5)  LSTEP(q0[6],  a6)  LSTEP(q0[7],  a7)
        LSTEP(q0[8],  a8)  LSTEP(q0[9],  a9)  LSTEP(q0[10], a10) LSTEP(q0[11], a11)
        LSTEP(q0[12], a12) LSTEP(q0[13], a13) LSTEP(q0[14], a14) LSTEP(q0[15], a15)
        LSTEP(q1[0],  b0)  LSTEP(q1[1],  b1)  LSTEP(q1[2],  b2)  LSTEP(q1[3],  b3)
        LSTEP(q1[4],  b4)  LSTEP(q1[5],  b5)  LSTEP(q1[6],  b6)  LSTEP(q1[7],  b7)
        LSTEP(q1[8],  b8)  LSTEP(q1[9],  b9)  LSTEP(q1[10], b10) LSTEP(q1[11], b11)
        LSTEP(q1[12], b12) LSTEP(q1[13], b13) LSTEP(q1[14], b14) LSTEP(q1[15], b15)
#undef LSTEP
#pragma unroll
        for (int off = 32; off > 0; off >>= 1) ls += __shfl_down(ls, off, 64);
        if (lane == 0)
            atomicAdd(loss_out, ls * (1.25f / (float)OUT_ELEMS));
    }
}

extern "C" void kernel_launch(void* const* d_in, const int* in_sizes, int n_in,
                              void* d_out, int out_size, void* d_ws, size_t ws_size,
                              hipStream_t stream) {
    const float* x   = (const float*)d_in[0];   // [64,32,32,64] fp32
    const float* emb = (const float*)d_in[1];   // [64,1024] fp32
    float* out       = (float*)d_out;           // [quantized | loss]
    float* eT        = (float*)d_ws;            // K*D fp32
    float* enorm     = eT + (size_t)K * D;      // K fp32
    float* loss_out  = out + OUT_ELEMS;

    vq_prep<<<dim3(K / 64), dim3(256), 0, stream>>>(emb, eT, enorm, loss_out);
    vq_main<<<dim3(NPTS / 128), dim3(256), 0, stream>>>(x, eT, enorm, out, loss_out);
}

// Round 8
// 184.327 us; speedup vs baseline: 1.0696x; 1.0696x over previous
//
#include <hip/hip_runtime.h>

#define D 64
#define K 1024
#define NPTS 65536
#define OUT_ELEMS (NPTS * D)
#define PAD4 17  // LDS out-slab row stride in float4 units

typedef __bf16 bf16x8 __attribute__((ext_vector_type(8)));
typedef float  f32x4  __attribute__((ext_vector_type(4)));

// d_ws layout (bytes): eT f32[K][64] @0 (262144) | enorm_half f32[K] @262144
// (4096) | ebh bf16[K][64] @266240 | ebm @397312 | ebl @528384 | end 659456.

// Ootomo split: v = h + m + l with each term bf16 (RN). h captures 2^-9,
// h+m 2^-18, h+m+l ~2^-27 relative.
static __device__ __forceinline__ void split1(float v, __bf16& h, __bf16& mid,
                                              __bf16& lo) {
    h = (__bf16)v;
    const float fh = (float)h;
    const float r1 = v - fh;          // exact (Sterbenz-class cancellation)
    mid = (__bf16)r1;
    const float fm = (float)mid;
    lo = (__bf16)(r1 - fm);
}

// ---------------------------------------------------------------------------
// Prep: LDS-tiled transpose emb[D][K] -> eT[K][D] f32 (exact codebook rows for
// the output gather) + bf16 3-term splits ebh/ebm/ebl [K][D] + enorm_half[k] =
// 0.5*||e_k||^2 in numpy axis-0 order; zero the loss slot.
// ---------------------------------------------------------------------------
__global__ __launch_bounds__(256) void vq_prep(const float* __restrict__ emb,
                                               float* __restrict__ eT,
                                               float* __restrict__ enorm_h,
                                               __bf16* __restrict__ ebh,
                                               __bf16* __restrict__ ebm,
                                               __bf16* __restrict__ ebl,
                                               float* __restrict__ loss_out) {
    __shared__ float tile[64][65];
    const int t    = threadIdx.x;
    const int lane = t & 63;
    const int quad = t >> 6;
    const int k0   = blockIdx.x * 64;

#pragma unroll
    for (int i = 0; i < 16; ++i) {
        const int d = i * 4 + quad;
        tile[d][lane] = emb[d * K + k0 + lane];
    }
    __syncthreads();

    const int kk = t >> 2, c = t & 3;
    const int krow = k0 + kk;
#pragma unroll
    for (int j = 0; j < 16; ++j) {
        const int d = c * 16 + j;
        const float v = tile[d][kk];
        const int idx = krow * D + d;
        eT[idx] = v;
        __bf16 h, mid, lo;
        split1(v, h, mid, lo);
        ebh[idx] = h; ebm[idx] = mid; ebl[idx] = lo;
    }

    if (t < 64) {   // np add.reduce axis 0: sequential over d
        float s = __fmul_rn(tile[0][t], tile[0][t]);
        for (int dd = 1; dd < D; ++dd)
            s = __fadd_rn(s, __fmul_rn(tile[dd][t], tile[dd][t]));
        enorm_h[k0 + t] = 0.5f * s;
    }
    if (blockIdx.x == 0 && t == 0) *loss_out = 0.0f;
}

// sequential sum of 8 squares (A-norm partial; loss-only, tolerance loose)
static __device__ __forceinline__ float sq8(float a, float b, float c, float d,
                                            float e, float f, float g, float h) {
    float r = __fmul_rn(a, a);
    r = __fadd_rn(r, __fmul_rn(b, b));
    r = __fadd_rn(r, __fmul_rn(c, c));
    r = __fadd_rn(r, __fmul_rn(d, d));
    r = __fadd_rn(r, __fmul_rn(e, e));
    r = __fadd_rn(r, __fmul_rn(f, f));
    r = __fadd_rn(r, __fmul_rn(g, g));
    r = __fadd_rn(r, __fmul_rn(h, h));
    return r;
}

#define PINF(v) asm volatile("" : "+v"(v))   // anti-remat/demote pin

#define MFMA(A, B, C) C = __builtin_amdgcn_mfma_f32_16x16x32_bf16(A, B, C, 0, 0, 0)

// Build one A-frag triple from 8 consecutive fp32 (two float4)
#define MKFRAG(FH, FM, FL, U0, U1) {                      \
    __bf16 h_, m_, l_;                                    \
    split1(U0.x, h_, m_, l_); FH[0]=h_; FM[0]=m_; FL[0]=l_; \
    split1(U0.y, h_, m_, l_); FH[1]=h_; FM[1]=m_; FL[1]=l_; \
    split1(U0.z, h_, m_, l_); FH[2]=h_; FM[2]=m_; FL[2]=l_; \
    split1(U0.w, h_, m_, l_); FH[3]=h_; FM[3]=m_; FL[3]=l_; \
    split1(U1.x, h_, m_, l_); FH[4]=h_; FM[4]=m_; FL[4]=l_; \
    split1(U1.y, h_, m_, l_); FH[5]=h_; FM[5]=m_; FL[5]=l_; \
    split1(U1.z, h_, m_, l_); FH[6]=h_; FM[6]=m_; FL[6]=l_; \
    split1(U1.w, h_, m_, l_); FH[7]=h_; FM[7]=m_; FL[7]=l_; }

// ---------------------------------------------------------------------------
// Main: block 256 = 4 waves; wave owns 32 points (2 MFMA row-tiles of 16,
// pts pbase + tile*16 + (lane&15)); scans ALL 1024 codes in 16-code tiles.
// Per code-tile: 6 prefetched B-frags (bf16 splits, per-lane 16B contiguous,
// B[k=quad*8+j][n=lane&15]) feed 24 MFMAs (2 tiles x 2 K-halves x 6 terms
// hh,mh,hm,mm,hl,lh -> dot to ~2e-7 abs). Argmin key = enorm/2 - dot
// (monotone in dist per point). Per-lane running (key, ct) per C-row; lex
// (key, idx) combine across the 16 col-classes. Winner rows gathered from
// exact fp32 eT; loss = A + 2*key* summed. Grid 512 = 2 blocks/CU.
// ---------------------------------------------------------------------------
__global__ __launch_bounds__(256, 2) void vq_main(const float* __restrict__ x,
        const float* __restrict__ eT, const float* __restrict__ enorm_h,
        const __bf16* __restrict__ ebh, const __bf16* __restrict__ ebm,
        const __bf16* __restrict__ ebl,
        float* __restrict__ out, float* __restrict__ loss_out) {
    // Aliased LDS: phase C uses skey/sct/rpart; phase D reuses the same
    // region as the output slab. swin is outside the slab span.
    __shared__ __align__(16) char smem[35328];
    float4* slab  = (float4*)smem;              // [128*17]   (phase D)
    float*  skey  = (float*)smem;               // [128][16]  (phase C)
    int*    sct   = (int*)(smem + 8192);        // [128][16]
    float*  rpart = (float*)(smem + 16384);     // [128][8]
    int*    swin  = (int*)(smem + 34816);       // [128]

    const int t     = threadIdx.x;
    const int lane  = t & 63;
    const int w     = t >> 6;
    const int m     = lane & 15;
    const int quad  = lane >> 4;
    const int pbase = blockIdx.x * 128 + w * 32;

    // ---- Phase A: x chunks -> norm partials + pinned A-frag splits ----
    bf16x8 Ah00, Am00, Al00, Ah01, Am01, Al01;   // tile0, halves 0/1
    bf16x8 Ah10, Am10, Al10, Ah11, Am11, Al11;   // tile1
#define LOADA(TT, HH, FH, FM, FL) {                                        \
    const float* px = x + ((size_t)(pbase + TT * 16 + m)) * D + HH * 32 + quad * 8; \
    const float4 u0 = *(const float4*)px;                                  \
    const float4 u1 = *(const float4*)(px + 4);                            \
    rpart[(w * 32 + TT * 16 + m) * 8 + (HH * 4 + quad)] =                  \
        sq8(u0.x, u0.y, u0.z, u0.w, u1.x, u1.y, u1.z, u1.w);               \
    MKFRAG(FH, FM, FL, u0, u1); }
    LOADA(0, 0, Ah00, Am00, Al00)
    LOADA(0, 1, Ah01, Am01, Al01)
    LOADA(1, 0, Ah10, Am10, Al10)
    LOADA(1, 1, Ah11, Am11, Al11)
#undef LOADA
    PINF(Ah00); PINF(Am00); PINF(Al00); PINF(Ah01); PINF(Am01); PINF(Al01);
    PINF(Ah10); PINF(Am10); PINF(Al10); PINF(Ah11); PINF(Am11); PINF(Al11);

    // ---- Phase B: k-loop over 64 code-tiles with B prefetch ----
    const size_t loff = (size_t)m * D + quad * 8;
    const __bf16* ph = ebh + loff;
    const __bf16* pm = ebm + loff;
    const __bf16* pl = ebl + loff;

    bf16x8 Bh0 = *(const bf16x8*)(ph);
    bf16x8 Bh1 = *(const bf16x8*)(ph + 32);
    bf16x8 Bm0 = *(const bf16x8*)(pm);
    bf16x8 Bm1 = *(const bf16x8*)(pm + 32);
    bf16x8 Bl0 = *(const bf16x8*)(pl);
    bf16x8 Bl1 = *(const bf16x8*)(pl + 32);
    float enh = enorm_h[m];

    const float FINF = 3.402823466e38f;
    float bk00 = FINF, bk01 = FINF, bk02 = FINF, bk03 = FINF;
    float bk10 = FINF, bk11 = FINF, bk12 = FINF, bk13 = FINF;
    int   bc00 = 0, bc01 = 0, bc02 = 0, bc03 = 0;
    int   bc10 = 0, bc11 = 0, bc12 = 0, bc13 = 0;

    for (int ct = 0; ct < 64; ++ct) {
        const int ctn = (ct + 1) & 63;                 // wrap: harmless read
        const size_t no = (size_t)ctn * 1024;
        const bf16x8 nBh0 = *(const bf16x8*)(ph + no);
        const bf16x8 nBh1 = *(const bf16x8*)(ph + no + 32);
        const bf16x8 nBm0 = *(const bf16x8*)(pm + no);
        const bf16x8 nBm1 = *(const bf16x8*)(pm + no + 32);
        const bf16x8 nBl0 = *(const bf16x8*)(pl + no);
        const bf16x8 nBl1 = *(const bf16x8*)(pl + no + 32);
        const float nenh  = enorm_h[ctn * 16 + m];

        f32x4 c0 = {0.f, 0.f, 0.f, 0.f};
        f32x4 c1 = {0.f, 0.f, 0.f, 0.f};
        MFMA(Ah00, Bh0, c0); MFMA(Ah10, Bh0, c1);      // hh
        MFMA(Ah01, Bh1, c0); MFMA(Ah11, Bh1, c1);
        MFMA(Am00, Bh0, c0); MFMA(Am10, Bh0, c1);      // mh
        MFMA(Am01, Bh1, c0); MFMA(Am11, Bh1, c1);
        MFMA(Ah00, Bm0, c0); MFMA(Ah10, Bm0, c1);      // hm
        MFMA(Ah01, Bm1, c0); MFMA(Ah11, Bm1, c1);
        MFMA(Am00, Bm0, c0); MFMA(Am10, Bm0, c1);      // mm
        MFMA(Am01, Bm1, c0); MFMA(Am11, Bm1, c1);
        MFMA(Ah00, Bl0, c0); MFMA(Ah10, Bl0, c1);      // hl
        MFMA(Ah01, Bl1, c0); MFMA(Ah11, Bl1, c1);
        MFMA(Al00, Bh0, c0); MFMA(Al10, Bh0, c1);      // lh
        MFMA(Al01, Bh1, c0); MFMA(Al11, Bh1, c1);

        // key = enorm/2 - dot; strict < (ct ascending) keeps lowest k in-class
        { const float k0v = enh - c0[0]; if (k0v < bk00) { bk00 = k0v; bc00 = ct; } }
        { const float k1v = enh - c0[1]; if (k1v < bk01) { bk01 = k1v; bc01 = ct; } }
        { const float k2v = enh - c0[2]; if (k2v < bk02) { bk02 = k2v; bc02 = ct; } }
        { const float k3v = enh - c0[3]; if (k3v < bk03) { bk03 = k3v; bc03 = ct; } }
        { const float k4v = enh - c1[0]; if (k4v < bk10) { bk10 = k4v; bc10 = ct; } }
        { const float k5v = enh - c1[1]; if (k5v < bk11) { bk11 = k5v; bc11 = ct; } }
        { const float k6v = enh - c1[2]; if (k6v < bk12) { bk12 = k6v; bc12 = ct; } }
        { const float k7v = enh - c1[3]; if (k7v < bk13) { bk13 = k7v; bc13 = ct; } }

        Bh0 = nBh0; Bh1 = nBh1; Bm0 = nBm0; Bm1 = nBm1; Bl0 = nBl0; Bl1 = nBl1;
        enh = nenh;
    }

    // C-layout: row = quad*4 + reg, col = m -> candidate class m of point row.
#define PUTC(TT, REG, BK, BC) {                                   \
    const int ploc = w * 32 + TT * 16 + quad * 4 + REG;           \
    skey[ploc * 16 + m] = BK; sct[ploc * 16 + m] = BC; }
    PUTC(0, 0, bk00, bc00) PUTC(0, 1, bk01, bc01)
    PUTC(0, 2, bk02, bc02) PUTC(0, 3, bk03, bc03)
    PUTC(1, 0, bk10, bc10) PUTC(1, 1, bk11, bc11)
    PUTC(1, 2, bk12, bc12) PUTC(1, 3, bk13, bc13)
#undef PUTC
    __syncthreads();

    // ---- Phase C (t<128): lex (key, idx) combine, winner idx, loss ----
    if (t < 128) {
        const int p = t;
        const float* rp = rpart + p * 8;
        const float A = ((rp[0] + rp[1]) + (rp[2] + rp[3])) +
                        ((rp[4] + rp[5]) + (rp[6] + rp[7]));
        float fb = FINF;
        int   fi = 0;
#pragma unroll
        for (int c = 0; c < 16; ++c) {
            const float kv = skey[p * 16 + c];
            const int   iv = sct[p * 16 + c] * 16 + c;
            if (kv < fb || (kv == fb && iv < fi)) { fb = kv; fi = iv; }
        }
        swin[p] = fi;
        float lp = fmaf(2.0f, fb, A);   // ||x-q||^2 = A + 2*key*
#pragma unroll
        for (int off = 32; off > 0; off >>= 1) lp += __shfl_down(lp, off, 64);
        if (lane == 0) atomicAdd(loss_out, lp * (1.25f / (float)OUT_ELEMS));
    }
    __syncthreads();

    // ---- Phase D: gather exact winner rows into slab, coalesced write ----
    {
        const int p = t >> 1, c = t & 1;
        const int fi = swin[p];
        const float4* qr = (const float4*)(eT + (size_t)fi * D) + c * 8;
        float4* dst = slab + p * PAD4 + c * 8;
#pragma unroll
        for (int jj = 0; jj < 8; ++jj) dst[jj] = qr[jj];
    }
    __syncthreads();
    float4* og = (float4*)out + (size_t)blockIdx.x * 2048;
#pragma unroll
    for (int s = 0; s < 8; ++s) {
        const int f = s * 256 + t;
        og[f] = slab[(f >> 4) * PAD4 + (f & 15)];
    }
}

extern "C" void kernel_launch(void* const* d_in, const int* in_sizes, int n_in,
                              void* d_out, int out_size, void* d_ws, size_t ws_size,
                              hipStream_t stream) {
    const float* x   = (const float*)d_in[0];   // [64,32,32,64] fp32
    const float* emb = (const float*)d_in[1];   // [64,1024] fp32
    float* out       = (float*)d_out;           // [quantized | loss]
    char*  ws        = (char*)d_ws;             // needs 659456 B
    float*  eT       = (float*)ws;
    float*  enorm_h  = (float*)(ws + 262144);
    __bf16* ebh      = (__bf16*)(ws + 266240);
    __bf16* ebm      = (__bf16*)(ws + 397312);
    __bf16* ebl      = (__bf16*)(ws + 528384);
    float* loss_out  = out + OUT_ELEMS;

    vq_prep<<<dim3(K / 64), dim3(256), 0, stream>>>(emb, eT, enorm_h, ebh, ebm,
                                                    ebl, loss_out);
    vq_main<<<dim3(NPTS / 128), dim3(256), 0, stream>>>(x, eT, enorm_h, ebh,
                                                        ebm, ebl, out, loss_out);
}

// Round 9
// 125.044 us; speedup vs baseline: 1.5767x; 1.4741x over previous
//
#include <hip/hip_runtime.h>

#define D 64
#define K 1024
#define NPTS 65536
#define OUT_ELEMS (NPTS * D)
#define PAD4 17  // LDS out-slab row stride in float4 units

typedef __bf16 bf16x8 __attribute__((ext_vector_type(8)));
typedef float  f32x4  __attribute__((ext_vector_type(4)));

// d_ws layout (bytes): eT f32[K][64] @0 (262144) | enorm_half f32[K] @262144
// (4096) | ebh bf16[K][64] @266240 | ebm @397312 | ebl @528384 | end 659456.

// Ootomo split: v = h + m + l, each bf16 (RN). h+m+l ~2^-27 relative.
static __device__ __forceinline__ void split1(float v, __bf16& h, __bf16& mid,
                                              __bf16& lo) {
    h = (__bf16)v;
    const float fh = (float)h;
    const float r1 = v - fh;          // exact
    mid = (__bf16)r1;
    const float fm = (float)mid;
    lo = (__bf16)(r1 - fm);
}

// ---------------------------------------------------------------------------
// Prep (unchanged from R8): tiled transpose emb[D][K] -> eT[K][D] f32 + bf16
// 3-term splits + enorm_half[k] = 0.5*||e_k||^2 (np axis-0 order); zero loss.
// ---------------------------------------------------------------------------
__global__ __launch_bounds__(256) void vq_prep(const float* __restrict__ emb,
                                               float* __restrict__ eT,
                                               float* __restrict__ enorm_h,
                                               __bf16* __restrict__ ebh,
                                               __bf16* __restrict__ ebm,
                                               __bf16* __restrict__ ebl,
                                               float* __restrict__ loss_out) {
    __shared__ float tile[64][65];
    const int t    = threadIdx.x;
    const int lane = t & 63;
    const int quad = t >> 6;
    const int k0   = blockIdx.x * 64;

#pragma unroll
    for (int i = 0; i < 16; ++i) {
        const int d = i * 4 + quad;
        tile[d][lane] = emb[d * K + k0 + lane];
    }
    __syncthreads();

    const int kk = t >> 2, c = t & 3;
    const int krow = k0 + kk;
#pragma unroll
    for (int j = 0; j < 16; ++j) {
        const int d = c * 16 + j;
        const float v = tile[d][kk];
        const int idx = krow * D + d;
        eT[idx] = v;
        __bf16 h, mid, lo;
        split1(v, h, mid, lo);
        ebh[idx] = h; ebm[idx] = mid; ebl[idx] = lo;
    }

    if (t < 64) {
        float s = __fmul_rn(tile[0][t], tile[0][t]);
        for (int dd = 1; dd < D; ++dd)
            s = __fadd_rn(s, __fmul_rn(tile[dd][t], tile[dd][t]));
        enorm_h[k0 + t] = 0.5f * s;
    }
    if (blockIdx.x == 0 && t == 0) *loss_out = 0.0f;
}

static __device__ __forceinline__ float sq8(float a, float b, float c, float d,
                                            float e, float f, float g, float h) {
    float r = __fmul_rn(a, a);
    r = __fadd_rn(r, __fmul_rn(b, b));
    r = __fadd_rn(r, __fmul_rn(c, c));
    r = __fadd_rn(r, __fmul_rn(d, d));
    r = __fadd_rn(r, __fmul_rn(e, e));
    r = __fadd_rn(r, __fmul_rn(f, f));
    r = __fadd_rn(r, __fmul_rn(g, g));
    r = __fadd_rn(r, __fmul_rn(h, h));
    return r;
}

#define PINF(v) asm volatile("" : "+v"(v))

#define MFMA(A, B, C) C = __builtin_amdgcn_mfma_f32_16x16x32_bf16(A, B, C, 0, 0, 0)

#define MKFRAG(FH, FM, FL, U0, U1) {                      \
    __bf16 h_, m_, l_;                                    \
    split1(U0.x, h_, m_, l_); FH[0]=h_; FM[0]=m_; FL[0]=l_; \
    split1(U0.y, h_, m_, l_); FH[1]=h_; FM[1]=m_; FL[1]=l_; \
    split1(U0.z, h_, m_, l_); FH[2]=h_; FM[2]=m_; FL[2]=l_; \
    split1(U0.w, h_, m_, l_); FH[3]=h_; FM[3]=m_; FL[3]=l_; \
    split1(U1.x, h_, m_, l_); FH[4]=h_; FM[4]=m_; FL[4]=l_; \
    split1(U1.y, h_, m_, l_); FH[5]=h_; FM[5]=m_; FL[5]=l_; \
    split1(U1.z, h_, m_, l_); FH[6]=h_; FM[6]=m_; FL[6]=l_; \
    split1(U1.w, h_, m_, l_); FH[7]=h_; FM[7]=m_; FL[7]=l_; }

// async global->LDS, 16B per lane; LDS dest = uniform base + lane*16.
static __device__ __forceinline__ void cp16(const void* gptr, void* lptr) {
    __builtin_amdgcn_global_load_lds(
        (const __attribute__((address_space(1))) void*)gptr,
        (__attribute__((address_space(3))) void*)lptr, 16, 0, 0);
}

// ---------------------------------------------------------------------------
// Main: block 256 = 4 waves, 128 points (wave w owns 32: 2 row-tiles of 16),
// all waves scan all 1024 codes in 16-code tiles. B tiles (3 bf16 splits,
// 2048 B each) are staged block-shared in double-buffered LDS via
// global_load_lds (no VGPRs to demote — the R8 pathology), swizzled
// (slot = n*8+((k8+n)&7), permuting SOURCE addresses since LDS dest is
// lane-linear) so the 6 ds_read_b128/iter are conflict-free. One barrier
// per iter; prefetch latency hides under ~930 cyc of MFMA pipe per SIMD.
// ---------------------------------------------------------------------------
__global__ __launch_bounds__(256, 2) void vq_main(const float* __restrict__ x,
        const float* __restrict__ eT, const float* __restrict__ enorm_h,
        const __bf16* __restrict__ ebh, const __bf16* __restrict__ ebm,
        const __bf16* __restrict__ ebl,
        float* __restrict__ out, float* __restrict__ loss_out) {
    // LDS: [0,12288) B staging 2 bufs x (h|m|l 2048 each)
    //      [12288,16384) rpart 128x8 f32   (phase A -> C, not aliased)
    //      [16384,16896) swin 128 i32      (phase C -> D)
    //      [16896,51712) aliased: skey 128x16 f32 @16896, sct @25088 (B->C);
    //                    slab 128*17 float4 @16896 (D).
    __shared__ __align__(16) char smem[51712];
    float*  rpart = (float*)(smem + 12288);
    int*    swin  = (int*)(smem + 16384);
    float*  skey  = (float*)(smem + 16896);
    int*    sct   = (int*)(smem + 25088);
    float4* slab  = (float4*)(smem + 16896);

    const int t     = threadIdx.x;
    const int lane  = t & 63;
    const int w     = t >> 6;
    const int m     = lane & 15;
    const int quad  = lane >> 4;
    const int pbase = blockIdx.x * 128 + w * 32;

    // ---- Staging-copy lane geometry (invariant) ----
    // Instruction (a, I) fills LDS slots I*64+lane (16B units) of array a.
    // Slot s = n*8 + j holds chunk (n = s>>3, k8 = (j - n) & 7):
    // source bytes = n*128 + k8*16 (+ I*1024 + ct*2048) within array a.
    const int n0   = lane >> 3;
    const int jj   = lane & 7;
    const int soff = n0 * 128 + (((jj - n0) & 7) << 4);
    // wave -> instrs: w0:(h,0)+(l,0), w1:(h,1)+(l,1), w2:(m,0), w3:(m,1).
    const char* gsA = (w <= 1) ? (const char*)ebh : (const char*)ebm;
    const int   IA  = w & 1;
    const int   dA  = ((w <= 1) ? 0 : 2048) + IA * 1024;   // LDS array+I offset
    const int   sA  = soff + IA * 1024;                     // src I offset
    const char* gsB = (const char*)ebl;
    const int   dB  = 4096 + w * 1024;                      // only w<=1
    const int   sB  = soff + w * 1024;

    // ds_read offsets for frag (H, array): o(H) = (m*8 + ((H*4+quad+m)&7))*16
    const int o0 = (m * 8 + ((quad + m) & 7)) * 16;         // H=0
    const int o1 = (m * 8 + ((4 + quad + m) & 7)) * 16;     // H=1

    // ---- Issue tile-0 staging, then do phase A under its latency ----
    cp16(gsA + sA, smem + dA);
    if (w <= 1) cp16(gsB + sB, smem + dB);

    // ---- Phase A: x -> norm partials + pinned A-frag splits ----
    bf16x8 Ah00, Am00, Al00, Ah01, Am01, Al01;
    bf16x8 Ah10, Am10, Al10, Ah11, Am11, Al11;
#define LOADA(TT, HH, FH, FM, FL) {                                        \
    const float* px = x + ((size_t)(pbase + TT * 16 + m)) * D + HH * 32 + quad * 8; \
    const float4 u0 = *(const float4*)px;                                  \
    const float4 u1 = *(const float4*)(px + 4);                            \
    rpart[(w * 32 + TT * 16 + m) * 8 + (HH * 4 + quad)] =                  \
        sq8(u0.x, u0.y, u0.z, u0.w, u1.x, u1.y, u1.z, u1.w);               \
    MKFRAG(FH, FM, FL, u0, u1); }
    LOADA(0, 0, Ah00, Am00, Al00)
    LOADA(0, 1, Ah01, Am01, Al01)
    LOADA(1, 0, Ah10, Am10, Al10)
    LOADA(1, 1, Ah11, Am11, Al11)
#undef LOADA
    PINF(Ah00); PINF(Am00); PINF(Al00); PINF(Ah01); PINF(Am01); PINF(Al01);
    PINF(Ah10); PINF(Am10); PINF(Al10); PINF(Ah11); PINF(Am11); PINF(Al11);

    __syncthreads();   // tile 0 staged + rpart visible

    // ---- Phase B: 64 code-tiles, LDS double-buffer, 1 barrier/iter ----
    const float FINF = 3.402823466e38f;
    float bk00 = FINF, bk01 = FINF, bk02 = FINF, bk03 = FINF;
    float bk10 = FINF, bk11 = FINF, bk12 = FINF, bk13 = FINF;
    int   bc00 = 0, bc01 = 0, bc02 = 0, bc03 = 0;
    int   bc10 = 0, bc11 = 0, bc12 = 0, bc13 = 0;

    for (int ct = 0; ct < 64; ++ct) {
        // prefetch tile ct+1 into the other buffer (wrap: harmless re-read)
        const int ctn = (ct + 1) & 63;
        const int nb  = ((ct + 1) & 1) * 6144;
        cp16(gsA + (size_t)ctn * 2048 + sA, smem + nb + dA);
        if (w <= 1) cp16(gsB + (size_t)ctn * 2048 + sB, smem + nb + dB);

        const float enh = enorm_h[ct * 16 + m];

        const char* bb = smem + (ct & 1) * 6144;
        const bf16x8 Bh0 = *(const bf16x8*)(bb + o0);
        const bf16x8 Bh1 = *(const bf16x8*)(bb + o1);
        const bf16x8 Bm0 = *(const bf16x8*)(bb + 2048 + o0);
        const bf16x8 Bm1 = *(const bf16x8*)(bb + 2048 + o1);
        const bf16x8 Bl0 = *(const bf16x8*)(bb + 4096 + o0);
        const bf16x8 Bl1 = *(const bf16x8*)(bb + 4096 + o1);

        f32x4 c0 = {0.f, 0.f, 0.f, 0.f};
        f32x4 c1 = {0.f, 0.f, 0.f, 0.f};
        MFMA(Ah00, Bh0, c0); MFMA(Ah10, Bh0, c1);      // hh
        MFMA(Ah01, Bh1, c0); MFMA(Ah11, Bh1, c1);
        MFMA(Am00, Bh0, c0); MFMA(Am10, Bh0, c1);      // mh
        MFMA(Am01, Bh1, c0); MFMA(Am11, Bh1, c1);
        MFMA(Ah00, Bm0, c0); MFMA(Ah10, Bm0, c1);      // hm
        MFMA(Ah01, Bm1, c0); MFMA(Ah11, Bm1, c1);
        MFMA(Am00, Bm0, c0); MFMA(Am10, Bm0, c1);      // mm
        MFMA(Am01, Bm1, c0); MFMA(Am11, Bm1, c1);
        MFMA(Ah00, Bl0, c0); MFMA(Ah10, Bl0, c1);      // hl
        MFMA(Ah01, Bl1, c0); MFMA(Ah11, Bl1, c1);
        MFMA(Al00, Bh0, c0); MFMA(Al10, Bh0, c1);      // lh
        MFMA(Al01, Bh1, c0); MFMA(Al11, Bh1, c1);

        { const float kv = enh - c0[0]; if (kv < bk00) { bk00 = kv; bc00 = ct; } }
        { const float kv = enh - c0[1]; if (kv < bk01) { bk01 = kv; bc01 = ct; } }
        { const float kv = enh - c0[2]; if (kv < bk02) { bk02 = kv; bc02 = ct; } }
        { const float kv = enh - c0[3]; if (kv < bk03) { bk03 = kv; bc03 = ct; } }
        { const float kv = enh - c1[0]; if (kv < bk10) { bk10 = kv; bc10 = ct; } }
        { const float kv = enh - c1[1]; if (kv < bk11) { bk11 = kv; bc11 = ct; } }
        { const float kv = enh - c1[2]; if (kv < bk12) { bk12 = kv; bc12 = ct; } }
        { const float kv = enh - c1[3]; if (kv < bk13) { bk13 = kv; bc13 = ct; } }

        __syncthreads();   // prefetch landed + all waves done reading buf
    }

    // C-layout: row = quad*4 + reg, col = m.
#define PUTC(TT, REG, BK, BC) {                                   \
    const int ploc = w * 32 + TT * 16 + quad * 4 + REG;           \
    skey[ploc * 16 + m] = BK; sct[ploc * 16 + m] = BC; }
    PUTC(0, 0, bk00, bc00) PUTC(0, 1, bk01, bc01)
    PUTC(0, 2, bk02, bc02) PUTC(0, 3, bk03, bc03)
    PUTC(1, 0, bk10, bc10) PUTC(1, 1, bk11, bc11)
    PUTC(1, 2, bk12, bc12) PUTC(1, 3, bk13, bc13)
#undef PUTC
    __syncthreads();

    // ---- Phase C (t<128): lex (key, idx) combine, winner idx, loss ----
    if (t < 128) {
        const int p = t;
        const float* rp = rpart + p * 8;
        const float A = ((rp[0] + rp[1]) + (rp[2] + rp[3])) +
                        ((rp[4] + rp[5]) + (rp[6] + rp[7]));
        float fb = FINF;
        int   fi = 0;
#pragma unroll
        for (int c = 0; c < 16; ++c) {
            const float kv = skey[p * 16 + c];
            const int   iv = sct[p * 16 + c] * 16 + c;
            if (kv < fb || (kv == fb && iv < fi)) { fb = kv; fi = iv; }
        }
        swin[p] = fi;
        float lp = fmaf(2.0f, fb, A);   // ||x-q||^2 = A + 2*key*
#pragma unroll
        for (int off = 32; off > 0; off >>= 1) lp += __shfl_down(lp, off, 64);
        if (lane == 0) atomicAdd(loss_out, lp * (1.25f / (float)OUT_ELEMS));
    }
    __syncthreads();

    // ---- Phase D: gather exact winner rows, coalesced slab write ----
    {
        const int p = t >> 1, c = t & 1;
        const int fi = swin[p];
        const float4* qr = (const float4*)(eT + (size_t)fi * D) + c * 8;
        float4* dst = slab + p * PAD4 + c * 8;
#pragma unroll
        for (int j = 0; j < 8; ++j) dst[j] = qr[j];
    }
    __syncthreads();
    float4* og = (float4*)out + (size_t)blockIdx.x * 2048;
#pragma unroll
    for (int s = 0; s < 8; ++s) {
        const int f = s * 256 + t;
        og[f] = slab[(f >> 4) * PAD4 + (f & 15)];
    }
}

extern "C" void kernel_launch(void* const* d_in, const int* in_sizes, int n_in,
                              void* d_out, int out_size, void* d_ws, size_t ws_size,
                              hipStream_t stream) {
    const float* x   = (const float*)d_in[0];   // [64,32,32,64] fp32
    const float* emb = (const float*)d_in[1];   // [64,1024] fp32
    float* out       = (float*)d_out;           // [quantized | loss]
    char*  ws        = (char*)d_ws;             // needs 659456 B
    float*  eT       = (float*)ws;
    float*  enorm_h  = (float*)(ws + 262144);
    __bf16* ebh      = (__bf16*)(ws + 266240);
    __bf16* ebm      = (__bf16*)(ws + 397312);
    __bf16* ebl      = (__bf16*)(ws + 528384);
    float* loss_out  = out + OUT_ELEMS;

    vq_prep<<<dim3(K / 64), dim3(256), 0, stream>>>(emb, eT, enorm_h, ebh, ebm,
                                                    ebl, loss_out);
    vq_main<<<dim3(NPTS / 128), dim3(256), 0, stream>>>(x, eT, enorm_h, ebh,
                                                        ebm, ebl, out, loss_out);
}

// Round 10
// 123.521 us; speedup vs baseline: 1.5962x; 1.0123x over previous
//
#include <hip/hip_runtime.h>

#define D 64
#define K 1024
#define NPTS 65536
#define OUT_ELEMS (NPTS * D)
#define PAD4 17  // LDS out-slab row stride in float4 units

typedef __bf16 bf16x8 __attribute__((ext_vector_type(8)));
typedef float  f32x4  __attribute__((ext_vector_type(4)));

// d_ws layout (bytes): eT f32[K][64] @0 (262144) | enorm_half f32[K] @262144
// (4096) | ebh bf16[K][64] @266240 | ebm @397312 | ebl @528384 | end 659456.

// Ootomo split: v = h + m + l, each bf16 (RN). h+m+l ~2^-27 relative.
static __device__ __forceinline__ void split1(float v, __bf16& h, __bf16& mid,
                                              __bf16& lo) {
    h = (__bf16)v;
    const float fh = (float)h;
    const float r1 = v - fh;          // exact
    mid = (__bf16)r1;
    const float fm = (float)mid;
    lo = (__bf16)(r1 - fm);
}

// ---------------------------------------------------------------------------
// Prep (unchanged, verified): tiled transpose emb[D][K] -> eT[K][D] f32 + bf16
// 3-term splits + enorm_half[k] = 0.5*||e_k||^2 (np axis-0 order); zero loss.
// ---------------------------------------------------------------------------
__global__ __launch_bounds__(256) void vq_prep(const float* __restrict__ emb,
                                               float* __restrict__ eT,
                                               float* __restrict__ enorm_h,
                                               __bf16* __restrict__ ebh,
                                               __bf16* __restrict__ ebm,
                                               __bf16* __restrict__ ebl,
                                               float* __restrict__ loss_out) {
    __shared__ float tile[64][65];
    const int t    = threadIdx.x;
    const int lane = t & 63;
    const int quad = t >> 6;
    const int k0   = blockIdx.x * 64;

#pragma unroll
    for (int i = 0; i < 16; ++i) {
        const int d = i * 4 + quad;
        tile[d][lane] = emb[d * K + k0 + lane];
    }
    __syncthreads();

    const int kk = t >> 2, c = t & 3;
    const int krow = k0 + kk;
#pragma unroll
    for (int j = 0; j < 16; ++j) {
        const int d = c * 16 + j;
        const float v = tile[d][kk];
        const int idx = krow * D + d;
        eT[idx] = v;
        __bf16 h, mid, lo;
        split1(v, h, mid, lo);
        ebh[idx] = h; ebm[idx] = mid; ebl[idx] = lo;
    }

    if (t < 64) {
        float s = __fmul_rn(tile[0][t], tile[0][t]);
        for (int dd = 1; dd < D; ++dd)
            s = __fadd_rn(s, __fmul_rn(tile[dd][t], tile[dd][t]));
        enorm_h[k0 + t] = 0.5f * s;
    }
    if (blockIdx.x == 0 && t == 0) *loss_out = 0.0f;
}

static __device__ __forceinline__ float sq8(float a, float b, float c, float d,
                                            float e, float f, float g, float h) {
    float r = __fmul_rn(a, a);
    r = __fadd_rn(r, __fmul_rn(b, b));
    r = __fadd_rn(r, __fmul_rn(c, c));
    r = __fadd_rn(r, __fmul_rn(d, d));
    r = __fadd_rn(r, __fmul_rn(e, e));
    r = __fadd_rn(r, __fmul_rn(f, f));
    r = __fadd_rn(r, __fmul_rn(g, g));
    r = __fadd_rn(r, __fmul_rn(h, h));
    return r;
}

#define PINF(v) asm volatile("" : "+v"(v))

#define MFMA(A, B, C) C = __builtin_amdgcn_mfma_f32_16x16x32_bf16(A, B, C, 0, 0, 0)

#define MKFRAG(FH, FM, FL, U0, U1) {                      \
    __bf16 h_, m_, l_;                                    \
    split1(U0.x, h_, m_, l_); FH[0]=h_; FM[0]=m_; FL[0]=l_; \
    split1(U0.y, h_, m_, l_); FH[1]=h_; FM[1]=m_; FL[1]=l_; \
    split1(U0.z, h_, m_, l_); FH[2]=h_; FM[2]=m_; FL[2]=l_; \
    split1(U0.w, h_, m_, l_); FH[3]=h_; FM[3]=m_; FL[3]=l_; \
    split1(U1.x, h_, m_, l_); FH[4]=h_; FM[4]=m_; FL[4]=l_; \
    split1(U1.y, h_, m_, l_); FH[5]=h_; FM[5]=m_; FL[5]=l_; \
    split1(U1.z, h_, m_, l_); FH[6]=h_; FM[6]=m_; FL[6]=l_; \
    split1(U1.w, h_, m_, l_); FH[7]=h_; FM[7]=m_; FL[7]=l_; }

// async global->LDS, 16B per lane; LDS dest = uniform base + lane*16.
static __device__ __forceinline__ void cp16(const void* gptr, void* lptr) {
    __builtin_amdgcn_global_load_lds(
        (const __attribute__((address_space(1))) void*)gptr,
        (__attribute__((address_space(3))) void*)lptr, 16, 0, 0);
}

// ---------------------------------------------------------------------------
// Main (R10): same math/layout as R9 (verified: absmax 9.77e-4, zero argmin
// flips), restructured K-loop. Per tile: __syncthreads FIRST (post-barrier vm
// queue empty -> ds_reads need no alias guard), then 6 ds_read_b128, THEN
// issue next tile's cp16s (pinned by sched_barrier so they can't sink), then
// 24 MFMAs. Every vmcnt drain now waits on loads issued one full MFMA block
// earlier (R9 drained the same-iter prefetch -> ~44% stall). Unroll x2 makes
// buffer parity compile-time. C split into H0/H1 partial accumulators (dep
// distance 2 -> 4), summed at tile end.
// ---------------------------------------------------------------------------
__global__ __launch_bounds__(256, 2) void vq_main(const float* __restrict__ x,
        const float* __restrict__ eT, const float* __restrict__ enorm_h,
        const __bf16* __restrict__ ebh, const __bf16* __restrict__ ebm,
        const __bf16* __restrict__ ebl,
        float* __restrict__ out, float* __restrict__ loss_out) {
    // LDS: [0,12288) B staging 2 bufs x (h|m|l 2048 each)
    //      [12288,16384) rpart 128x8 f32, [16384,16896) swin 128 i32,
    //      [16896,51712) aliased: skey@16896 / sct@25088 (B->C); slab@16896 (D)
    __shared__ __align__(16) char smem[51712];
    float*  rpart = (float*)(smem + 12288);
    int*    swin  = (int*)(smem + 16384);
    float*  skey  = (float*)(smem + 16896);
    int*    sct   = (int*)(smem + 25088);
    float4* slab  = (float4*)(smem + 16896);

    const int t     = threadIdx.x;
    const int lane  = t & 63;
    const int w     = t >> 6;
    const int m     = lane & 15;
    const int quad  = lane >> 4;
    const int pbase = blockIdx.x * 128 + w * 32;

    // Staging-copy lane geometry (R9-verified):
    const int n0   = lane >> 3;
    const int jj   = lane & 7;
    const int soff = n0 * 128 + (((jj - n0) & 7) << 4);
    const char* gsA = (w <= 1) ? (const char*)ebh : (const char*)ebm;
    const int   IA  = w & 1;
    const int   dA  = ((w <= 1) ? 0 : 2048) + IA * 1024;
    const int   sA  = soff + IA * 1024;
    const char* gsB = (const char*)ebl;
    const int   dB  = 4096 + w * 1024;
    const int   sB  = soff + w * 1024;

    // ds_read offsets (R9-verified swizzle):
    const int o0 = (m * 8 + ((quad + m) & 7)) * 16;
    const int o1 = (m * 8 + ((4 + quad + m) & 7)) * 16;

    // ---- Issue tile-0 staging; phase A hides its latency ----
    cp16(gsA + sA, smem + dA);
    if (w <= 1) cp16(gsB + sB, smem + dB);

    // ---- Phase A: x -> norm partials + pinned A-frag splits ----
    bf16x8 Ah00, Am00, Al00, Ah01, Am01, Al01;
    bf16x8 Ah10, Am10, Al10, Ah11, Am11, Al11;
#define LOADA(TT, HH, FH, FM, FL) {                                        \
    const float* px = x + ((size_t)(pbase + TT * 16 + m)) * D + HH * 32 + quad * 8; \
    const float4 u0 = *(const float4*)px;                                  \
    const float4 u1 = *(const float4*)(px + 4);                            \
    rpart[(w * 32 + TT * 16 + m) * 8 + (HH * 4 + quad)] =                  \
        sq8(u0.x, u0.y, u0.z, u0.w, u1.x, u1.y, u1.z, u1.w);               \
    MKFRAG(FH, FM, FL, u0, u1); }
    LOADA(0, 0, Ah00, Am00, Al00)
    LOADA(0, 1, Ah01, Am01, Al01)
    LOADA(1, 0, Ah10, Am10, Al10)
    LOADA(1, 1, Ah11, Am11, Al11)
#undef LOADA
    PINF(Ah00); PINF(Am00); PINF(Al00); PINF(Ah01); PINF(Am01); PINF(Al01);
    PINF(Ah10); PINF(Am10); PINF(Al10); PINF(Ah11); PINF(Am11); PINF(Al11);

    // ---- Phase B: 64 tiles, unroll x2 (compile-time buffer parity) ----
    const float FINF = 3.402823466e38f;
    float bk00 = FINF, bk01 = FINF, bk02 = FINF, bk03 = FINF;
    float bk10 = FINF, bk11 = FINF, bk12 = FINF, bk13 = FINF;
    int   bc00 = 0, bc01 = 0, bc02 = 0, bc03 = 0;
    int   bc10 = 0, bc11 = 0, bc12 = 0, bc13 = 0;

#define TILE_BODY(BBOFF, CT, PRET, PREOFF) {                               \
    __syncthreads();  /* drains cp16 issued one full tile ago */           \
    const char* bb = smem + (BBOFF);                                       \
    const bf16x8 Bh0 = *(const bf16x8*)(bb + o0);                          \
    const bf16x8 Bh1 = *(const bf16x8*)(bb + o1);                          \
    const bf16x8 Bm0 = *(const bf16x8*)(bb + 2048 + o0);                   \
    const bf16x8 Bm1 = *(const bf16x8*)(bb + 2048 + o1);                   \
    const bf16x8 Bl0 = *(const bf16x8*)(bb + 4096 + o0);                   \
    const bf16x8 Bl1 = *(const bf16x8*)(bb + 4096 + o1);                   \
    cp16(gsA + (size_t)(PRET) * 2048 + sA, smem + (PREOFF) + dA);          \
    if (w <= 1) cp16(gsB + (size_t)(PRET) * 2048 + sB, smem + (PREOFF) + dB); \
    __builtin_amdgcn_sched_barrier(0);  /* pin issue point */              \
    const float enh = enorm_h[(CT) * 16 + m];                              \
    f32x4 c0a = {0.f,0.f,0.f,0.f}, c0b = {0.f,0.f,0.f,0.f};                \
    f32x4 c1a = {0.f,0.f,0.f,0.f}, c1b = {0.f,0.f,0.f,0.f};                \
    MFMA(Ah00, Bh0, c0a); MFMA(Ah10, Bh0, c1a);                            \
    MFMA(Ah01, Bh1, c0b); MFMA(Ah11, Bh1, c1b);                            \
    MFMA(Am00, Bh0, c0a); MFMA(Am10, Bh0, c1a);                            \
    MFMA(Am01, Bh1, c0b); MFMA(Am11, Bh1, c1b);                            \
    MFMA(Ah00, Bm0, c0a); MFMA(Ah10, Bm0, c1a);                            \
    MFMA(Ah01, Bm1, c0b); MFMA(Ah11, Bm1, c1b);                            \
    MFMA(Am00, Bm0, c0a); MFMA(Am10, Bm0, c1a);                            \
    MFMA(Am01, Bm1, c0b); MFMA(Am11, Bm1, c1b);                            \
    MFMA(Ah00, Bl0, c0a); MFMA(Ah10, Bl0, c1a);                            \
    MFMA(Ah01, Bl1, c0b); MFMA(Ah11, Bl1, c1b);                            \
    MFMA(Al00, Bh0, c0a); MFMA(Al10, Bh0, c1a);                            \
    MFMA(Al01, Bh1, c0b); MFMA(Al11, Bh1, c1b);                            \
    const f32x4 c0 = c0a + c0b;                                            \
    const f32x4 c1 = c1a + c1b;                                            \
    { const float kv = enh - c0[0]; if (kv < bk00) { bk00 = kv; bc00 = (CT); } } \
    { const float kv = enh - c0[1]; if (kv < bk01) { bk01 = kv; bc01 = (CT); } } \
    { const float kv = enh - c0[2]; if (kv < bk02) { bk02 = kv; bc02 = (CT); } } \
    { const float kv = enh - c0[3]; if (kv < bk03) { bk03 = kv; bc03 = (CT); } } \
    { const float kv = enh - c1[0]; if (kv < bk10) { bk10 = kv; bc10 = (CT); } } \
    { const float kv = enh - c1[1]; if (kv < bk11) { bk11 = kv; bc11 = (CT); } } \
    { const float kv = enh - c1[2]; if (kv < bk12) { bk12 = kv; bc12 = (CT); } } \
    { const float kv = enh - c1[3]; if (kv < bk13) { bk13 = kv; bc13 = (CT); } } }

    for (int j = 0; j < 32; ++j) {
        const int ct0 = 2 * j;
        const int ct1 = 2 * j + 1;
        const int tp2 = (2 * j + 2) & 63;   // wrap at the end: harmless re-read
        TILE_BODY(0,    ct0, ct1, 6144)     // read buf0, prefetch -> buf1
        TILE_BODY(6144, ct1, tp2, 0)        // read buf1, prefetch -> buf0
    }
#undef TILE_BODY

    // C-layout: row = quad*4 + reg, col = m.
#define PUTC(TT, REG, BK, BC) {                                   \
    const int ploc = w * 32 + TT * 16 + quad * 4 + REG;           \
    skey[ploc * 16 + m] = BK; sct[ploc * 16 + m] = BC; }
    PUTC(0, 0, bk00, bc00) PUTC(0, 1, bk01, bc01)
    PUTC(0, 2, bk02, bc02) PUTC(0, 3, bk03, bc03)
    PUTC(1, 0, bk10, bc10) PUTC(1, 1, bk11, bc11)
    PUTC(1, 2, bk12, bc12) PUTC(1, 3, bk13, bc13)
#undef PUTC
    __syncthreads();

    // ---- Phase C (t<128): lex (key, idx) combine, winner idx, loss ----
    if (t < 128) {
        const int p = t;
        const float* rp = rpart + p * 8;
        const float A = ((rp[0] + rp[1]) + (rp[2] + rp[3])) +
                        ((rp[4] + rp[5]) + (rp[6] + rp[7]));
        float fb = FINF;
        int   fi = 0;
#pragma unroll
        for (int c = 0; c < 16; ++c) {
            const float kv = skey[p * 16 + c];
            const int   iv = sct[p * 16 + c] * 16 + c;
            if (kv < fb || (kv == fb && iv < fi)) { fb = kv; fi = iv; }
        }
        swin[p] = fi;
        float lp = fmaf(2.0f, fb, A);   // ||x-q||^2 = A + 2*key*
#pragma unroll
        for (int off = 32; off > 0; off >>= 1) lp += __shfl_down(lp, off, 64);
        if (lane == 0) atomicAdd(loss_out, lp * (1.25f / (float)OUT_ELEMS));
    }
    __syncthreads();

    // ---- Phase D: gather exact winner rows, coalesced slab write ----
    {
        const int p = t >> 1, c = t & 1;
        const int fi = swin[p];
        const float4* qr = (const float4*)(eT + (size_t)fi * D) + c * 8;
        float4* dst = slab + p * PAD4 + c * 8;
#pragma unroll
        for (int j = 0; j < 8; ++j) dst[j] = qr[j];
    }
    __syncthreads();
    float4* og = (float4*)out + (size_t)blockIdx.x * 2048;
#pragma unroll
    for (int s = 0; s < 8; ++s) {
        const int f = s * 256 + t;
        og[f] = slab[(f >> 4) * PAD4 + (f & 15)];
    }
}

extern "C" void kernel_launch(void* const* d_in, const int* in_sizes, int n_in,
                              void* d_out, int out_size, void* d_ws, size_t ws_size,
                              hipStream_t stream) {
    const float* x   = (const float*)d_in[0];   // [64,32,32,64] fp32
    const float* emb = (const float*)d_in[1];   // [64,1024] fp32
    float* out       = (float*)d_out;           // [quantized | loss]
    char*  ws        = (char*)d_ws;             // needs 659456 B
    float*  eT       = (float*)ws;
    float*  enorm_h  = (float*)(ws + 262144);
    __bf16* ebh      = (__bf16*)(ws + 266240);
    __bf16* ebm      = (__bf16*)(ws + 397312);
    __bf16* ebl      = (__bf16*)(ws + 528384);
    float* loss_out  = out + OUT_ELEMS;

    vq_prep<<<dim3(K / 64), dim3(256), 0, stream>>>(emb, eT, enorm_h, ebh, ebm,
                                                    ebl, loss_out);
    vq_main<<<dim3(NPTS / 128), dim3(256), 0, stream>>>(x, eT, enorm_h, ebh,
                                                        ebm, ebl, out, loss_out);
}

// Round 11
// 122.459 us; speedup vs baseline: 1.6100x; 1.0087x over previous
//
#include <hip/hip_runtime.h>

#define D 64
#define K 1024
#define NPTS 65536
#define OUT_ELEMS (NPTS * D)
#define PAD4 17  // LDS out-slab row stride in float4 units

typedef __bf16 bf16x8 __attribute__((ext_vector_type(8)));
typedef float  f32x4  __attribute__((ext_vector_type(4)));

// d_ws layout (bytes): eT f32[K][64] @0 (262144) | enorm_half f32[K] @262144
// (4096) | ebh bf16[K][64] @266240 | ebm @397312 | ebl @528384 | end 659456.

// Ootomo split: v = h + m + l, each bf16 (RN). h+m+l ~2^-27 relative.
static __device__ __forceinline__ void split1(float v, __bf16& h, __bf16& mid,
                                              __bf16& lo) {
    h = (__bf16)v;
    const float fh = (float)h;
    const float r1 = v - fh;          // exact
    mid = (__bf16)r1;
    const float fm = (float)mid;
    lo = (__bf16)(r1 - fm);
}

// ---------------------------------------------------------------------------
// Prep (unchanged, verified): tiled transpose emb[D][K] -> eT[K][D] f32 + bf16
// 3-term splits + enorm_half[k] = 0.5*||e_k||^2 (np axis-0 order); zero loss.
// ---------------------------------------------------------------------------
__global__ __launch_bounds__(256) void vq_prep(const float* __restrict__ emb,
                                               float* __restrict__ eT,
                                               float* __restrict__ enorm_h,
                                               __bf16* __restrict__ ebh,
                                               __bf16* __restrict__ ebm,
                                               __bf16* __restrict__ ebl,
                                               float* __restrict__ loss_out) {
    __shared__ float tile[64][65];
    const int t    = threadIdx.x;
    const int lane = t & 63;
    const int quad = t >> 6;
    const int k0   = blockIdx.x * 64;

#pragma unroll
    for (int i = 0; i < 16; ++i) {
        const int d = i * 4 + quad;
        tile[d][lane] = emb[d * K + k0 + lane];
    }
    __syncthreads();

    const int kk = t >> 2, c = t & 3;
    const int krow = k0 + kk;
#pragma unroll
    for (int j = 0; j < 16; ++j) {
        const int d = c * 16 + j;
        const float v = tile[d][kk];
        const int idx = krow * D + d;
        eT[idx] = v;
        __bf16 h, mid, lo;
        split1(v, h, mid, lo);
        ebh[idx] = h; ebm[idx] = mid; ebl[idx] = lo;
    }

    if (t < 64) {
        float s = __fmul_rn(tile[0][t], tile[0][t]);
        for (int dd = 1; dd < D; ++dd)
            s = __fadd_rn(s, __fmul_rn(tile[dd][t], tile[dd][t]));
        enorm_h[k0 + t] = 0.5f * s;
    }
    if (blockIdx.x == 0 && t == 0) *loss_out = 0.0f;
}

static __device__ __forceinline__ float sq8(float a, float b, float c, float d,
                                            float e, float f, float g, float h) {
    float r = __fmul_rn(a, a);
    r = __fadd_rn(r, __fmul_rn(b, b));
    r = __fadd_rn(r, __fmul_rn(c, c));
    r = __fadd_rn(r, __fmul_rn(d, d));
    r = __fadd_rn(r, __fmul_rn(e, e));
    r = __fadd_rn(r, __fmul_rn(f, f));
    r = __fadd_rn(r, __fmul_rn(g, g));
    r = __fadd_rn(r, __fmul_rn(h, h));
    return r;
}

#define PINF(v) asm volatile("" : "+v"(v))

#define MFMA(A, B, C) C = __builtin_amdgcn_mfma_f32_16x16x32_bf16(A, B, C, 0, 0, 0)

#define MKFRAG(FH, FM, FL, U0, U1) {                      \
    __bf16 h_, m_, l_;                                    \
    split1(U0.x, h_, m_, l_); FH[0]=h_; FM[0]=m_; FL[0]=l_; \
    split1(U0.y, h_, m_, l_); FH[1]=h_; FM[1]=m_; FL[1]=l_; \
    split1(U0.z, h_, m_, l_); FH[2]=h_; FM[2]=m_; FL[2]=l_; \
    split1(U0.w, h_, m_, l_); FH[3]=h_; FM[3]=m_; FL[3]=l_; \
    split1(U1.x, h_, m_, l_); FH[4]=h_; FM[4]=m_; FL[4]=l_; \
    split1(U1.y, h_, m_, l_); FH[5]=h_; FM[5]=m_; FL[5]=l_; \
    split1(U1.z, h_, m_, l_); FH[6]=h_; FM[6]=m_; FL[6]=l_; \
    split1(U1.w, h_, m_, l_); FH[7]=h_; FM[7]=m_; FL[7]=l_; }

// async global->LDS, 16B per lane; LDS dest = uniform base + lane*16.
static __device__ __forceinline__ void cp16(const void* gptr, void* lptr) {
    __builtin_amdgcn_global_load_lds(
        (const __attribute__((address_space(1))) void*)gptr,
        (__attribute__((address_space(3))) void*)lptr, 16, 0, 0);
}

// ---------------------------------------------------------------------------
// Main (R11): same verified math/layout (absmax 9.77e-4, zero argmin flips
// across R8-R10); 2x the wave parallelism. Block = 512 thr = 8 waves, 128
// points; wave owns 16 points (1 MFMA row-tile, 6 pinned A-frags = 24 VGPRs)
// and scans all 1024 codes: 12 MFMAs/tile in 2 acc chains. Grid 512 x 2
// blocks/CU -> 4 waves/SIMD (R9/R10 had 2: grid-capped occupancy was the
// bottleneck — R10's scheduling changes were exactly neutral). Per-SIMD pipe
// demand unchanged (48 MFMA/tile = 933 cyc) but latency now hides under TLP.
// Staging: waves 0-5 issue one cp16 each (array w>>1, half w&1), double-
// buffered, swizzled LDS (R9-verified geometry).
// ---------------------------------------------------------------------------
__global__ __launch_bounds__(512, 4) void vq_main(const float* __restrict__ x,
        const float* __restrict__ eT, const float* __restrict__ enorm_h,
        const __bf16* __restrict__ ebh, const __bf16* __restrict__ ebm,
        const __bf16* __restrict__ ebl,
        float* __restrict__ out, float* __restrict__ loss_out) {
    // LDS: [0,12288) B staging 2 bufs x (h|m|l 2048 each)
    //      [12288,16384) rpart 128x8 f32, [16384,16896) swin 128 i32,
    //      [16896,51712) aliased: skey@16896 / sct@25088 (B->C); slab@16896 (D)
    __shared__ __align__(16) char smem[51712];
    float*  rpart = (float*)(smem + 12288);
    int*    swin  = (int*)(smem + 16384);
    float*  skey  = (float*)(smem + 16896);
    int*    sct   = (int*)(smem + 25088);
    float4* slab  = (float4*)(smem + 16896);

    const int t     = threadIdx.x;
    const int lane  = t & 63;
    const int w     = t >> 6;          // 0..7
    const int m     = lane & 15;
    const int quad  = lane >> 4;
    const int pbase = blockIdx.x * 128 + w * 16;

    // Staging-copy lane geometry (R9-verified): slot s = n*8+j holds source
    // chunk n*128 + ((j-n)&7)*16 within (array, half).
    const int n0   = lane >> 3;
    const int jj   = lane & 7;
    const int soff = n0 * 128 + (((jj - n0) & 7) << 4);
    // wave w<6 stages (array w>>1, half w&1); waves 6,7 idle on staging.
    const char* gsA = (w < 2) ? (const char*)ebh
                    : (w < 4) ? (const char*)ebm : (const char*)ebl;
    const int   IA  = w & 1;
    const int   dA  = (w >> 1) * 2048 + IA * 1024;   // LDS offset (w<6 only)
    const int   sA  = soff + IA * 1024;

    // ds_read offsets (R9-verified swizzle): o(H) = (m*8+((H*4+quad+m)&7))*16
    const int o0 = (m * 8 + ((quad + m) & 7)) * 16;
    const int o1 = (m * 8 + ((4 + quad + m) & 7)) * 16;

    // ---- Issue tile-0 staging; phase A hides its latency ----
    if (w < 6) cp16(gsA + sA, smem + dA);

    // ---- Phase A: x -> norm partials + 6 pinned A-frag splits ----
    bf16x8 Ah0, Am0, Al0, Ah1, Am1, Al1;
#define LOADA(HH, FH, FM, FL) {                                            \
    const float* px = x + ((size_t)(pbase + m)) * D + HH * 32 + quad * 8;  \
    const float4 u0 = *(const float4*)px;                                  \
    const float4 u1 = *(const float4*)(px + 4);                            \
    rpart[(w * 16 + m) * 8 + (HH * 4 + quad)] =                            \
        sq8(u0.x, u0.y, u0.z, u0.w, u1.x, u1.y, u1.z, u1.w);               \
    MKFRAG(FH, FM, FL, u0, u1); }
    LOADA(0, Ah0, Am0, Al0)
    LOADA(1, Ah1, Am1, Al1)
#undef LOADA
    PINF(Ah0); PINF(Am0); PINF(Al0); PINF(Ah1); PINF(Am1); PINF(Al1);

    // ---- Phase B: 64 code-tiles, double-buffered, unroll x2 ----
    const float FINF = 3.402823466e38f;
    float bk0 = FINF, bk1 = FINF, bk2 = FINF, bk3 = FINF;
    int   bc0 = 0, bc1 = 0, bc2 = 0, bc3 = 0;

#define TILE_BODY(BBOFF, CT, PRET, PREOFF) {                               \
    __syncthreads();  /* buf ready; prev prefetch had a full tile slack */ \
    if (w < 6) cp16(gsA + (size_t)(PRET) * 2048 + sA, smem + (PREOFF) + dA); \
    const char* bb = smem + (BBOFF);                                       \
    const bf16x8 Bh0 = *(const bf16x8*)(bb + o0);                          \
    const bf16x8 Bh1 = *(const bf16x8*)(bb + o1);                          \
    const bf16x8 Bm0 = *(const bf16x8*)(bb + 2048 + o0);                   \
    const bf16x8 Bm1 = *(const bf16x8*)(bb + 2048 + o1);                   \
    const bf16x8 Bl0 = *(const bf16x8*)(bb + 4096 + o0);                   \
    const bf16x8 Bl1 = *(const bf16x8*)(bb + 4096 + o1);                   \
    const float enh = enorm_h[(CT) * 16 + m];                              \
    f32x4 ca = {0.f,0.f,0.f,0.f}, cb = {0.f,0.f,0.f,0.f};                  \
    MFMA(Ah0, Bh0, ca); MFMA(Ah1, Bh1, cb);   /* hh */                     \
    MFMA(Am0, Bh0, ca); MFMA(Am1, Bh1, cb);   /* mh */                     \
    MFMA(Ah0, Bm0, ca); MFMA(Ah1, Bm1, cb);   /* hm */                     \
    MFMA(Am0, Bm0, ca); MFMA(Am1, Bm1, cb);   /* mm */                     \
    MFMA(Ah0, Bl0, ca); MFMA(Ah1, Bl1, cb);   /* hl */                     \
    MFMA(Al0, Bh0, ca); MFMA(Al1, Bh1, cb);   /* lh */                     \
    const f32x4 c0 = ca + cb;                                              \
    { const float kv = enh - c0[0]; if (kv < bk0) { bk0 = kv; bc0 = (CT); } } \
    { const float kv = enh - c0[1]; if (kv < bk1) { bk1 = kv; bc1 = (CT); } } \
    { const float kv = enh - c0[2]; if (kv < bk2) { bk2 = kv; bc2 = (CT); } } \
    { const float kv = enh - c0[3]; if (kv < bk3) { bk3 = kv; bc3 = (CT); } } }

    for (int j = 0; j < 32; ++j) {
        const int ct0 = 2 * j;
        const int ct1 = 2 * j + 1;
        const int tp2 = (2 * j + 2) & 63;   // wrap at end: harmless re-read
        TILE_BODY(0,    ct0, ct1, 6144)     // read buf0, prefetch -> buf1
        TILE_BODY(6144, ct1, tp2, 0)        // read buf1, prefetch -> buf0
    }
#undef TILE_BODY

    // C-layout: row = quad*4 + reg, col = m.
#define PUTC(REG, BK, BC) {                                       \
    const int ploc = w * 16 + quad * 4 + REG;                     \
    skey[ploc * 16 + m] = BK; sct[ploc * 16 + m] = BC; }
    PUTC(0, bk0, bc0) PUTC(1, bk1, bc1) PUTC(2, bk2, bc2) PUTC(3, bk3, bc3)
#undef PUTC
    __syncthreads();

    // ---- Phase C (t<128, waves 0-1): lex (key, idx) combine + loss ----
    if (t < 128) {
        const int p = t;
        const float* rp = rpart + p * 8;
        const float A = ((rp[0] + rp[1]) + (rp[2] + rp[3])) +
                        ((rp[4] + rp[5]) + (rp[6] + rp[7]));
        float fb = FINF;
        int   fi = 0;
#pragma unroll
        for (int c = 0; c < 16; ++c) {
            const float kv = skey[p * 16 + c];
            const int   iv = sct[p * 16 + c] * 16 + c;
            if (kv < fb || (kv == fb && iv < fi)) { fb = kv; fi = iv; }
        }
        swin[p] = fi;
        float lp = fmaf(2.0f, fb, A);   // ||x-q||^2 = A + 2*key*
#pragma unroll
        for (int off = 32; off > 0; off >>= 1) lp += __shfl_down(lp, off, 64);
        if (lane == 0) atomicAdd(loss_out, lp * (1.25f / (float)OUT_ELEMS));
    }
    __syncthreads();

    // ---- Phase D: gather exact winner rows, coalesced slab write ----
    {
        const int p = t >> 2, c = t & 3;   // 4 threads per point
        const int fi = swin[p];
        const float4* qr = (const float4*)(eT + (size_t)fi * D) + c * 4;
        float4* dst = slab + p * PAD4 + c * 4;
#pragma unroll
        for (int j = 0; j < 4; ++j) dst[j] = qr[j];
    }
    __syncthreads();
    float4* og = (float4*)out + (size_t)blockIdx.x * 2048;
#pragma unroll
    for (int s = 0; s < 4; ++s) {
        const int f = s * 512 + t;
        og[f] = slab[(f >> 4) * PAD4 + (f & 15)];
    }
}

extern "C" void kernel_launch(void* const* d_in, const int* in_sizes, int n_in,
                              void* d_out, int out_size, void* d_ws, size_t ws_size,
                              hipStream_t stream) {
    const float* x   = (const float*)d_in[0];   // [64,32,32,64] fp32
    const float* emb = (const float*)d_in[1];   // [64,1024] fp32
    float* out       = (float*)d_out;           // [quantized | loss]
    char*  ws        = (char*)d_ws;             // needs 659456 B
    float*  eT       = (float*)ws;
    float*  enorm_h  = (float*)(ws + 262144);
    __bf16* ebh      = (__bf16*)(ws + 266240);
    __bf16* ebm      = (__bf16*)(ws + 397312);
    __bf16* ebl      = (__bf16*)(ws + 528384);
    float* loss_out  = out + OUT_ELEMS;

    vq_prep<<<dim3(K / 64), dim3(256), 0, stream>>>(emb, eT, enorm_h, ebh, ebm,
                                                    ebl, loss_out);
    vq_main<<<dim3(NPTS / 128), dim3(512), 0, stream>>>(x, eT, enorm_h, ebh,
                                                        ebm, ebl, out, loss_out);
}

// Round 12
// 113.879 us; speedup vs baseline: 1.7313x; 1.0753x over previous
//
#include <hip/hip_runtime.h>

#define D 64
#define K 1024
#define NPTS 65536
#define OUT_ELEMS (NPTS * D)
#define PAD4 17  // LDS out-slab row stride in float4 units

typedef _Float16 f16x8 __attribute__((ext_vector_type(8)));
typedef float    f32x4 __attribute__((ext_vector_type(4)));

#define SCL  4096.0f            // 2^12
#define ISCL 0.000244140625f    // 2^-12

// d_ws layout (bytes): eT f32[K][64] @0 (262144) | enorm_half f32[K] @262144
// (4096) | eh f16[K][64] @266240 (131072) | els f16[K][64] @397312 | end 528384.

// Scaled f16 2-way split: v = h + ls*2^-12. h = RN16(v) (11-bit mantissa);
// ls = RN16((v-h)*2^12) is normal-range (~|v| scale) -> no subnormal-flush
// hazard; residual ~2^-24|v|.
static __device__ __forceinline__ void split16(float v, _Float16& h, _Float16& ls) {
    h = (_Float16)v;
    const float r = (v - (float)h) * SCL;   // exact scaling (pow2)
    ls = (_Float16)r;
}

// ---------------------------------------------------------------------------
// Prep: tiled transpose emb[D][K] -> eT[K][D] f32 (exact rows for the output
// gather) + f16 h/ls split arrays + enorm_half[k] = 0.5*||e_k||^2 in numpy
// axis-0 order; zero the loss slot.
// ---------------------------------------------------------------------------
__global__ __launch_bounds__(256) void vq_prep(const float* __restrict__ emb,
                                               float* __restrict__ eT,
                                               float* __restrict__ enorm_h,
                                               _Float16* __restrict__ eh,
                                               _Float16* __restrict__ els,
                                               float* __restrict__ loss_out) {
    __shared__ float tile[64][65];
    const int t    = threadIdx.x;
    const int lane = t & 63;
    const int quad = t >> 6;
    const int k0   = blockIdx.x * 64;

#pragma unroll
    for (int i = 0; i < 16; ++i) {
        const int d = i * 4 + quad;
        tile[d][lane] = emb[d * K + k0 + lane];
    }
    __syncthreads();

    const int kk = t >> 2, c = t & 3;
    const int krow = k0 + kk;
#pragma unroll
    for (int j = 0; j < 16; ++j) {
        const int d = c * 16 + j;
        const float v = tile[d][kk];
        const int idx = krow * D + d;
        eT[idx] = v;
        _Float16 h, ls;
        split16(v, h, ls);
        eh[idx] = h; els[idx] = ls;
    }

    if (t < 64) {   // np add.reduce axis 0: sequential over d
        float s = __fmul_rn(tile[0][t], tile[0][t]);
        for (int dd = 1; dd < D; ++dd)
            s = __fadd_rn(s, __fmul_rn(tile[dd][t], tile[dd][t]));
        enorm_h[k0 + t] = 0.5f * s;
    }
    if (blockIdx.x == 0 && t == 0) *loss_out = 0.0f;
}

static __device__ __forceinline__ float sq8(float a, float b, float c, float d,
                                            float e, float f, float g, float h) {
    float r = __fmul_rn(a, a);
    r = __fadd_rn(r, __fmul_rn(b, b));
    r = __fadd_rn(r, __fmul_rn(c, c));
    r = __fadd_rn(r, __fmul_rn(d, d));
    r = __fadd_rn(r, __fmul_rn(e, e));
    r = __fadd_rn(r, __fmul_rn(f, f));
    r = __fadd_rn(r, __fmul_rn(g, g));
    r = __fadd_rn(r, __fmul_rn(h, h));
    return r;
}

#define PINF(v) asm volatile("" : "+v"(v))

#define MFMA(A, B, C) C = __builtin_amdgcn_mfma_f32_16x16x32_f16(A, B, C, 0, 0, 0)

#define MKFRAG16(FH, FS, U0, U1) {                        \
    _Float16 h_, s_;                                      \
    split16(U0.x, h_, s_); FH[0]=h_; FS[0]=s_;            \
    split16(U0.y, h_, s_); FH[1]=h_; FS[1]=s_;            \
    split16(U0.z, h_, s_); FH[2]=h_; FS[2]=s_;            \
    split16(U0.w, h_, s_); FH[3]=h_; FS[3]=s_;            \
    split16(U1.x, h_, s_); FH[4]=h_; FS[4]=s_;            \
    split16(U1.y, h_, s_); FH[5]=h_; FS[5]=s_;            \
    split16(U1.z, h_, s_); FH[6]=h_; FS[6]=s_;            \
    split16(U1.w, h_, s_); FH[7]=h_; FS[7]=s_; }

// async global->LDS, 16B per lane; LDS dest = uniform base + lane*16.
static __device__ __forceinline__ void cp16(const void* gptr, void* lptr) {
    __builtin_amdgcn_global_load_lds(
        (const __attribute__((address_space(1))) void*)gptr,
        (__attribute__((address_space(3))) void*)lptr, 16, 0, 0);
}

// ---------------------------------------------------------------------------
// Main (R12): f16 scaled 3-term dot (replaces bf16 6-term; equal ~2e-7 error,
// half the MFMAs) + code-half split-K. Block = 512 thr = 8 waves = 4 point-
// groups x 2 code-halves; wave owns 32 points (2 row-tiles) x its 512 codes.
// Grid 512 -> 2 blocks/CU = 4 waves/SIMD AND 32 pts/wave: LDS B-broadcast
// reads = 32/CU/tile (384 cyc) < MFMA 932/iter — R11's LDS-pipe bind removed.
// Per iter (2 tiles, one per half): 8 cp16 (1/wave), 4 ds_read_b128/wave,
// 12 MFMAs/wave (2 rowtiles x {hh, ls*eh, xh*els} x 2 K-halves, scaled
// correction folded once per tile). Argmin: 32 classes/pt, lex (key, idx).
// ---------------------------------------------------------------------------
__global__ __launch_bounds__(512, 4) void vq_main(const float* __restrict__ x,
        const float* __restrict__ eT, const float* __restrict__ enorm_h,
        const _Float16* __restrict__ eh, const _Float16* __restrict__ els,
        float* __restrict__ out, float* __restrict__ loss_out) {
    // LDS: [0,16384) staging 2 bufs x 8192 (half h @h*4096: eh@0, els@2048)
    //      [16384,20480) rpart 128x8 f32, [20480,20992) swin 128 i32,
    //      [20992,55808) aliased: skey 128x32 @20992, sct @37376 (B->C);
    //                    slab 128*17 float4 @20992 (D).
    __shared__ __align__(16) char smem[55808];
    float*  rpart = (float*)(smem + 16384);
    int*    swin  = (int*)(smem + 20480);
    float*  skey  = (float*)(smem + 20992);
    int*    sct   = (int*)(smem + 37376);
    float4* slab  = (float4*)(smem + 20992);

    const int t     = threadIdx.x;
    const int lane  = t & 63;
    const int w     = t >> 6;          // 0..7
    const int m     = lane & 15;
    const int quad  = lane >> 4;
    const int g     = w >> 1;          // point-group 0..3
    const int h     = w & 1;           // code-half 0..1
    const int pbase = blockIdx.x * 128 + g * 32;

    // Staging: wave w stages unit (hs = w>>2, array as = (w>>1)&1, I = w&1).
    // R9-verified swizzle: LDS slot lane holds source soff within the 1KB
    // (8-code) unit; read offsets o0/o1 below match.
    const int n0   = lane >> 3;
    const int jj   = lane & 7;
    const int soff = n0 * 128 + (((jj - n0) & 7) << 4);
    const int hs   = w >> 2;
    const char* gsrc = ((w >> 1) & 1) ? (const char*)els : (const char*)eh;
    const char* gsb  = gsrc + (w & 1) * 1024 + soff;       // + tile*2048
    const int   dA   = hs * 4096 + ((w >> 1) & 1) * 2048 + (w & 1) * 1024;

    // Read offsets within a 2KB array region (R9-verified):
    const int o0 = (m * 8 + ((quad + m) & 7)) * 16;        // K-half 0
    const int o1 = (m * 8 + ((4 + quad + m) & 7)) * 16;    // K-half 1

    // ---- Stage tile 0 (both halves); phase A hides the latency ----
    cp16(gsb + (size_t)(hs * 32) * 2048, smem + dA);

    // ---- Phase A: x -> norm partials + 8 pinned A-frags (2 rowtiles) ----
    f16x8 Ah00, As00, Ah01, As01;   // rowtile 0, K-halves 0/1
    f16x8 Ah10, As10, Ah11, As11;   // rowtile 1
#define LOADA(TT, HH, FH, FS) {                                            \
    const float* px = x + ((size_t)(pbase + TT * 16 + m)) * D + HH * 32 + quad * 8; \
    const float4 u0 = *(const float4*)px;                                  \
    const float4 u1 = *(const float4*)(px + 4);                            \
    if (h == 0)                                                            \
        rpart[(g * 32 + TT * 16 + m) * 8 + (HH * 4 + quad)] =              \
            sq8(u0.x, u0.y, u0.z, u0.w, u1.x, u1.y, u1.z, u1.w);           \
    MKFRAG16(FH, FS, u0, u1); }
    LOADA(0, 0, Ah00, As00)
    LOADA(0, 1, Ah01, As01)
    LOADA(1, 0, Ah10, As10)
    LOADA(1, 1, Ah11, As11)
#undef LOADA
    PINF(Ah00); PINF(As00); PINF(Ah01); PINF(As01);
    PINF(Ah10); PINF(As10); PINF(Ah11); PINF(As11);

    // ---- Phase B: 32 iterations (each covers one 16-code tile per half) ----
    const float FINF = 3.402823466e38f;
    float bk00 = FINF, bk01 = FINF, bk02 = FINF, bk03 = FINF;
    float bk10 = FINF, bk11 = FINF, bk12 = FINF, bk13 = FINF;
    int   bc00 = 0, bc01 = 0, bc02 = 0, bc03 = 0;
    int   bc10 = 0, bc11 = 0, bc12 = 0, bc13 = 0;

#define TILE_BODY(BBOFF, CT, PRET, PREOFF) {                               \
    __syncthreads();  /* buf ready; prefetch had a full iter of slack */   \
    cp16(gsb + (size_t)(hs * 32 + (PRET)) * 2048, smem + (PREOFF) + dA);   \
    const char* bb = smem + (BBOFF) + h * 4096;                            \
    const f16x8 Bh0 = *(const f16x8*)(bb + o0);                            \
    const f16x8 Bh1 = *(const f16x8*)(bb + o1);                            \
    const f16x8 Bs0 = *(const f16x8*)(bb + 2048 + o0);                     \
    const f16x8 Bs1 = *(const f16x8*)(bb + 2048 + o1);                     \
    const float enh = enorm_h[h * 512 + (CT) * 16 + m];                    \
    f32x4 m0a = {0.f,0.f,0.f,0.f}, m0b = {0.f,0.f,0.f,0.f};                \
    f32x4 c0a = {0.f,0.f,0.f,0.f}, c0b = {0.f,0.f,0.f,0.f};                \
    f32x4 m1a = {0.f,0.f,0.f,0.f}, m1b = {0.f,0.f,0.f,0.f};                \
    f32x4 c1a = {0.f,0.f,0.f,0.f}, c1b = {0.f,0.f,0.f,0.f};                \
    MFMA(Ah00, Bh0, m0a); MFMA(Ah10, Bh0, m1a);   /* hh K-half 0 */        \
    MFMA(Ah01, Bh1, m0b); MFMA(Ah11, Bh1, m1b);   /* hh K-half 1 */        \
    MFMA(As00, Bh0, c0a); MFMA(As10, Bh0, c1a);   /* xls*eh */             \
    MFMA(As01, Bh1, c0b); MFMA(As11, Bh1, c1b);                            \
    MFMA(Ah00, Bs0, c0a); MFMA(Ah10, Bs0, c1a);   /* xh*els */             \
    MFMA(Ah01, Bs1, c0b); MFMA(Ah11, Bs1, c1b);                            \
    const f32x4 d0 = (m0a + m0b) + ISCL * (c0a + c0b);                     \
    const f32x4 d1 = (m1a + m1b) + ISCL * (c1a + c1b);                     \
    { const float kv = enh - d0[0]; if (kv < bk00) { bk00 = kv; bc00 = (CT); } } \
    { const float kv = enh - d0[1]; if (kv < bk01) { bk01 = kv; bc01 = (CT); } } \
    { const float kv = enh - d0[2]; if (kv < bk02) { bk02 = kv; bc02 = (CT); } } \
    { const float kv = enh - d0[3]; if (kv < bk03) { bk03 = kv; bc03 = (CT); } } \
    { const float kv = enh - d1[0]; if (kv < bk10) { bk10 = kv; bc10 = (CT); } } \
    { const float kv = enh - d1[1]; if (kv < bk11) { bk11 = kv; bc11 = (CT); } } \
    { const float kv = enh - d1[2]; if (kv < bk12) { bk12 = kv; bc12 = (CT); } } \
    { const float kv = enh - d1[3]; if (kv < bk13) { bk13 = kv; bc13 = (CT); } } }

    for (int j = 0; j < 16; ++j) {
        const int ct0 = 2 * j;
        const int ct1 = 2 * j + 1;
        const int tp2 = (2 * j + 2) & 31;   // wrap at end: harmless re-read
        TILE_BODY(0,    ct0, ct1, 8192)     // read buf0, prefetch -> buf1
        TILE_BODY(8192, ct1, tp2, 0)        // read buf1, prefetch -> buf0
    }
#undef TILE_BODY

    // C-layout: row = quad*4 + reg, col = m; class = h*16 + m (32 classes).
#define PUTC(TT, REG, BK, BC) {                                   \
    const int ploc = g * 32 + TT * 16 + quad * 4 + REG;           \
    skey[ploc * 32 + h * 16 + m] = BK;                            \
    sct [ploc * 32 + h * 16 + m] = BC; }
    PUTC(0, 0, bk00, bc00) PUTC(0, 1, bk01, bc01)
    PUTC(0, 2, bk02, bc02) PUTC(0, 3, bk03, bc03)
    PUTC(1, 0, bk10, bc10) PUTC(1, 1, bk11, bc11)
    PUTC(1, 2, bk12, bc12) PUTC(1, 3, bk13, bc13)
#undef PUTC
    __syncthreads();

    // ---- Phase C (t<128): lex (key, idx) combine over 32 classes ----
    if (t < 128) {
        const int p = t;
        const float* rp = rpart + p * 8;
        const float A = ((rp[0] + rp[1]) + (rp[2] + rp[3])) +
                        ((rp[4] + rp[5]) + (rp[6] + rp[7]));
        float fb = FINF;
        int   fi = 0;
#pragma unroll
        for (int c = 0; c < 32; ++c) {
            const float kv = skey[p * 32 + c];
            const int   iv = (c >> 4) * 512 + sct[p * 32 + c] * 16 + (c & 15);
            if (kv < fb || (kv == fb && iv < fi)) { fb = kv; fi = iv; }
        }
        swin[p] = fi;
        float lp = fmaf(2.0f, fb, A);   // ||x-q||^2 = A + 2*key*
#pragma unroll
        for (int off = 32; off > 0; off >>= 1) lp += __shfl_down(lp, off, 64);
        if (lane == 0) atomicAdd(loss_out, lp * (1.25f / (float)OUT_ELEMS));
    }
    __syncthreads();

    // ---- Phase D: gather exact winner rows, coalesced slab write ----
    {
        const int p = t >> 2, c = t & 3;   // 4 threads per point
        const int fi = swin[p];
        const float4* qr = (const float4*)(eT + (size_t)fi * D) + c * 4;
        float4* dst = slab + p * PAD4 + c * 4;
#pragma unroll
        for (int j = 0; j < 4; ++j) dst[j] = qr[j];
    }
    __syncthreads();
    float4* og = (float4*)out + (size_t)blockIdx.x * 2048;
#pragma unroll
    for (int s = 0; s < 4; ++s) {
        const int f = s * 512 + t;
        og[f] = slab[(f >> 4) * PAD4 + (f & 15)];
    }
}

extern "C" void kernel_launch(void* const* d_in, const int* in_sizes, int n_in,
                              void* d_out, int out_size, void* d_ws, size_t ws_size,
                              hipStream_t stream) {
    const float* x   = (const float*)d_in[0];   // [64,32,32,64] fp32
    const float* emb = (const float*)d_in[1];   // [64,1024] fp32
    float* out       = (float*)d_out;           // [quantized | loss]
    char*  ws        = (char*)d_ws;             // needs 528384 B
    float*    eT      = (float*)ws;
    float*    enorm_h = (float*)(ws + 262144);
    _Float16* eh      = (_Float16*)(ws + 266240);
    _Float16* els     = (_Float16*)(ws + 397312);
    float* loss_out   = out + OUT_ELEMS;

    vq_prep<<<dim3(K / 64), dim3(256), 0, stream>>>(emb, eT, enorm_h, eh, els,
                                                    loss_out);
    vq_main<<<dim3(NPTS / 128), dim3(512), 0, stream>>>(x, eT, enorm_h, eh,
                                                        els, out, loss_out);
}